// Round 1
// baseline (382.998 us; speedup 1.0000x reference)
//
#include <hip/hip_runtime.h>
#include <hip/hip_bf16.h>

#define F_DIM 64
#define K_DIM 132      // 2F+4
#define H_DIM 128
#define KP    160      // K padded to 5*32 for mfma_16x16x32
#define LROW  168      // row stride (bf16 elems) for A-lds and W_t: 336 B, 84 dwords, 84%32=20 -> max 2-way bank alias (free)
#define MT    64       // edges per block

typedef __attribute__((ext_vector_type(8))) short short8;   // 8 bf16 = 4 VGPRs (mfma A/B frag)
typedef __attribute__((ext_vector_type(4))) float f32x4;    // mfma C/D frag

__device__ __forceinline__ unsigned short f2bf(float f) {
    __hip_bfloat16 h = __float2bfloat16(f);
    return __builtin_bit_cast(unsigned short, h);
}

__device__ __forceinline__ float angle3(float ax, float ay, float az,
                                        float bx, float by, float bz) {
    float cx = ay*bz - az*by;
    float cy = az*bx - ax*bz;
    float cz = ax*by - ay*bx;
    float cn = sqrtf(cx*cx + cy*cy + cz*cz);
    float d  = ax*bx + ay*by + az*bz;
    return atan2f(cn, d);
}

// W [K,H] f32 -> W_t [H][LROW] bf16 (zero-padded past K_DIM)
__global__ void build_wt(const float* __restrict__ W, unsigned short* __restrict__ wt) {
    int g = blockIdx.x * blockDim.x + threadIdx.x;
    if (g >= H_DIM * LROW) return;
    int n = g / LROW, k = g % LROW;
    float v = (k < K_DIM) ? W[k * H_DIM + n] : 0.0f;
    wt[n * LROW + k] = f2bf(v);
}

__global__ void scatter_slots(const int* __restrict__ idx, int* __restrict__ node2slot, int S) {
    int s = blockIdx.x * blockDim.x + threadIdx.x;
    if (s < S) node2slot[idx[s]] = s;   // duplicate idx: any winner is a valid canonical slot
}

__global__ __launch_bounds__(256, 2)
void edge_kernel(const float* __restrict__ x, const float* __restrict__ pos,
                 const float* __restrict__ normal, const unsigned short* __restrict__ wt,
                 const float* __restrict__ bias, const int* __restrict__ edge,
                 const int* __restrict__ node2slot, float* __restrict__ agg, int E) {
    __shared__ __align__(16) unsigned short a_lds[MT * LROW];
    __shared__ int slot_lds[MT];

    const int tid = threadIdx.x;

    // ---- stage A: edge_attr = [x[e1] | x[e0] | ppf | 0-pad] as bf16, rows = edges ----
    {
        int m = tid >> 2;          // edge row 0..63
        int p = tid & 3;           // 32-feature chunk: p<2 -> x[e1], p>=2 -> x[e0]
        int e = blockIdx.x * MT + m;
        int e0 = 0, e1 = 0;
        if (e < E) { e0 = edge[e]; e1 = edge[E + e]; }
        const float* src = (p < 2) ? (x + (size_t)e1 * F_DIM + p * 32)
                                   : (x + (size_t)e0 * F_DIM + (p - 2) * 32);
        const f32x4* s4 = (const f32x4*)src;
        uint4* dst = (uint4*)(a_lds + m * LROW + p * 32);
        #pragma unroll
        for (int i = 0; i < 4; ++i) {
            f32x4 f0 = s4[2*i], f1 = s4[2*i + 1];
            uint4 q;
            q.x = (unsigned)f2bf(f0.x) | ((unsigned)f2bf(f0.y) << 16);
            q.y = (unsigned)f2bf(f0.z) | ((unsigned)f2bf(f0.w) << 16);
            q.z = (unsigned)f2bf(f1.x) | ((unsigned)f2bf(f1.y) << 16);
            q.w = (unsigned)f2bf(f1.z) | ((unsigned)f2bf(f1.w) << 16);
            dst[i] = q;
        }
    }
    if (tid < MT) {
        int m = tid;
        int e = blockIdx.x * MT + m;
        float p4[4] = {0.f, 0.f, 0.f, 0.f};
        int slot = -1;
        if (e < E) {
            int e0 = edge[e], e1 = edge[E + e];
            slot = node2slot[e1];
            float px = pos[3*e0]   - pos[3*e1];
            float py = pos[3*e0+1] - pos[3*e1+1];
            float pz = pos[3*e0+2] - pos[3*e1+2];
            float n0x = normal[3*e0], n0y = normal[3*e0+1], n0z = normal[3*e0+2];
            float n1x = normal[3*e1], n1y = normal[3*e1+1], n1z = normal[3*e1+2];
            p4[0] = sqrtf(px*px + py*py + pz*pz);
            p4[1] = angle3(n1x,n1y,n1z, px,py,pz);
            p4[2] = angle3(n0x,n0y,n0z, px,py,pz);
            p4[3] = angle3(n1x,n1y,n1z, n0x,n0y,n0z);
        }
        slot_lds[m] = slot;
        uint2 pp;
        pp.x = (unsigned)f2bf(p4[0]) | ((unsigned)f2bf(p4[1]) << 16);
        pp.y = (unsigned)f2bf(p4[2]) | ((unsigned)f2bf(p4[3]) << 16);
        *(uint2*)(a_lds + m * LROW + 128) = pp;          // k 128..131 = ppf
        *(uint2*)(a_lds + m * LROW + 132) = make_uint2(0, 0);  // k 132..135
        uint4 z = make_uint4(0, 0, 0, 0);
        uint4* zp = (uint4*)(a_lds + m * LROW + 136);    // k 136..167
        zp[0] = z; zp[1] = z; zp[2] = z; zp[3] = z;
    }
    __syncthreads();

    // ---- MFMA: [64 x KP] @ [KP x 128], wave w covers cols [w*32, w*32+32) ----
    const int wv   = tid >> 6;
    const int lane = tid & 63;
    const int l15  = lane & 15;
    const int quad = lane >> 4;
    const int n0 = wv * 32 + l15;
    const int n1 = n0 + 16;
    const float b0 = bias[n0];
    const float b1 = bias[n1];

    f32x4 acc[4][2];
    #pragma unroll
    for (int i = 0; i < 4; ++i)
        #pragma unroll
        for (int j = 0; j < 2; ++j)
            acc[i][j] = (f32x4){0.f, 0.f, 0.f, 0.f};

    #pragma unroll
    for (int ks = 0; ks < 5; ++ks) {
        const int ko = ks * 32 + quad * 8;
        short8 bf0 = *(const short8*)(wt + (size_t)n0 * LROW + ko);
        short8 bf1 = *(const short8*)(wt + (size_t)n1 * LROW + ko);
        #pragma unroll
        for (int mt = 0; mt < 4; ++mt) {
            short8 af = *(const short8*)(a_lds + (mt * 16 + l15) * LROW + ko);
            acc[mt][0] = __builtin_amdgcn_mfma_f32_16x16x32_bf16(af, bf0, acc[mt][0], 0, 0, 0);
            acc[mt][1] = __builtin_amdgcn_mfma_f32_16x16x32_bf16(af, bf1, acc[mt][1], 0, 0, 0);
        }
    }

    // ---- epilogue: bias + relu + atomicMax (all values >= 0, int-ordered) ----
    #pragma unroll
    for (int mt = 0; mt < 4; ++mt) {
        #pragma unroll
        for (int r = 0; r < 4; ++r) {
            int m = mt * 16 + quad * 4 + r;   // C/D layout: row = quad*4 + reg
            int slot = slot_lds[m];
            if (slot < 0) continue;
            float v0 = fmaxf(acc[mt][0][r] + b0, 0.f);
            float v1 = fmaxf(acc[mt][1][r] + b1, 0.f);
            atomicMax((int*)(agg + (size_t)slot * H_DIM + n0), __float_as_int(v0));
            atomicMax((int*)(agg + (size_t)slot * H_DIM + n1), __float_as_int(v1));
        }
    }
}

// duplicate-idx fixup (copies write only non-canonical rows, read only canonical) + pos gather
__global__ void finalize(const int* __restrict__ idx, const int* __restrict__ node2slot,
                         const float* __restrict__ pos, float* __restrict__ out, int S) {
    int g = blockIdx.x * blockDim.x + threadIdx.x;
    int total = S * H_DIM;
    if (g < total) {
        int s = g >> 7, c = g & 127;
        int node = idx[s];
        int sp = node2slot[node];
        if (sp != s) out[g] = out[(size_t)sp * H_DIM + c];
    } else if (g < total + 3 * S) {
        int g2 = g - total;
        int s = g2 / 3, j = g2 - 3 * s;
        out[total + g2] = pos[(size_t)idx[s] * 3 + j];
    }
}

extern "C" void kernel_launch(void* const* d_in, const int* in_sizes, int n_in,
                              void* d_out, int out_size, void* d_ws, size_t ws_size,
                              hipStream_t stream) {
    const float* x      = (const float*)d_in[0];
    const float* pos    = (const float*)d_in[1];
    const float* normal = (const float*)d_in[2];
    const float* W      = (const float*)d_in[3];
    const float* b      = (const float*)d_in[4];
    const int*   edge   = (const int*)d_in[5];
    const int*   idx    = (const int*)d_in[6];

    const int H = in_sizes[4];            // 128
    const int K = in_sizes[3] / H;        // 132
    const int F = (K - 4) / 2;            // 64
    const int N = in_sizes[0] / F;        // 100000
    const int E = in_sizes[5] / 2;        // 800000
    const int S = in_sizes[6];            // 25000

    // ws layout: W_t bf16 [128*168] (43008 B) | node2slot [N] int (400000 B)
    unsigned short* wt = (unsigned short*)d_ws;
    int* node2slot = (int*)((char*)d_ws + (size_t)H_DIM * LROW * sizeof(unsigned short));
    float* out = (float*)d_out;           // first S*H floats double as the compact agg buffer

    hipMemsetAsync(node2slot, 0xFF, (size_t)N * sizeof(int), stream);   // -1
    hipMemsetAsync(out, 0, (size_t)S * H * sizeof(float), stream);      // agg init (= empty-segment 0)

    build_wt<<<(H_DIM * LROW + 255) / 256, 256, 0, stream>>>(W, wt);
    scatter_slots<<<(S + 255) / 256, 256, 0, stream>>>(idx, node2slot, S);
    edge_kernel<<<(E + MT - 1) / MT, 256, 0, stream>>>(x, pos, normal, wt, b, edge,
                                                       node2slot, out, E);
    finalize<<<(S * H + 3 * S + 255) / 256, 256, 0, stream>>>(idx, node2slot, pos, out, S);
}